// Round 8
// baseline (412.165 us; speedup 1.0000x reference)
//
#include <hip/hip_runtime.h>

#define BB 2
#define CC 1024
#define HH 16
#define TT 2048
#define SS 2048
#define LL 2048   // T == S

typedef unsigned short u16;
typedef __attribute__((ext_vector_type(8))) short short8;
typedef __attribute__((ext_vector_type(4))) float f32x4;
typedef __attribute__((ext_vector_type(4))) unsigned short us4;

__device__ __forceinline__ u16 f2bf(float f) {
    union { float f; unsigned int i; } x; x.f = f;
    unsigned int r = x.i + 0x7FFFu + ((x.i >> 16) & 1u);
    return (u16)(r >> 16);
}

// ---------- QKV projection GEMM (transpose fused into B staging) ----------
// Out[o][l] = sum_c W[o][c] * X[b][c][l] + bias[o]   (fp32 in, bf16 out)
// p=0: Q*0.125 -> Qb [b][h][t][64]; p=1: K -> Kb [b][h][s][64]; p=2: V -> Vb [b][o][s]
__global__ __launch_bounds__(256) void qkv_gemm(
    const float* __restrict__ target, const float* __restrict__ source,
    const float* __restrict__ Wq, const float* __restrict__ bq,
    const float* __restrict__ Wk, const float* __restrict__ bk,
    const float* __restrict__ Wv, const float* __restrict__ bv,
    u16* __restrict__ Qb, u16* __restrict__ Kb, u16* __restrict__ Vb)
{
    const int p = blockIdx.z >> 1;
    const int b = blockIdx.z & 1;
    const float* W    = (p == 0) ? Wq : (p == 1) ? Wk : Wv;
    const float* bias = (p == 0) ? bq : (p == 1) ? bk : bv;
    const float* X    = ((p == 0) ? target : source) + (size_t)b * CC * LL;

    const int m0 = blockIdx.y * 128;   // o
    const int n0 = blockIdx.x * 128;   // l (token)

    __shared__ __align__(16) u16 As[128 * 72];  // As[o_local][c_local]
    __shared__ __align__(16) u16 Bs[128 * 72];  // Bs[l_local][c_local]

    const int tid  = threadIdx.x;
    const int lane = tid & 63;
    const int wid  = tid >> 6;
    const int ln   = lane & 15;
    const int q    = lane >> 4;
    const int wm   = (wid >> 1) * 64;
    const int wn   = (wid & 1) * 64;

    f32x4 acc[4][4];
#pragma unroll
    for (int i = 0; i < 4; i++)
#pragma unroll
        for (int j = 0; j < 4; j++) acc[i][j] = (f32x4){0.f, 0.f, 0.f, 0.f};

    const int arow_s = tid >> 3;       // 0..31
    const int ach    = tid & 7;        // 8-elem chunk within 64-elem c-slab
    const int lp     = tid & 31;       // l-patch (4 l each)
    const int cp0    = tid >> 5;       // 0..7 (c-patch base)

    for (int k0 = 0; k0 < CC; k0 += 64) {
        __syncthreads();
        // --- stage A: W[o][c] fp32 -> bf16, row-major ---
#pragma unroll
        for (int i = 0; i < 4; i++) {
            const int row = arow_s + i * 32;
            const float* wp = W + (size_t)(m0 + row) * CC + k0 + ach * 8;
            f32x4 w0 = *(const f32x4*)wp;
            f32x4 w1 = *(const f32x4*)(wp + 4);
            short8 av;
#pragma unroll
            for (int j = 0; j < 4; j++) { av[j] = (short)f2bf(w0[j]); av[4 + j] = (short)f2bf(w1[j]); }
            *(short8*)(As + row * 72 + ach * 8) = av;
        }
        // --- stage B with transpose: X[c][l] fp32 -> Bs[l][c] bf16, 4x4 patches ---
#pragma unroll
        for (int i = 0; i < 2; i++) {
            const int cpi = cp0 + i * 8;    // c-patch 0..15 (4 c each)
            const float* xp = X + (size_t)(k0 + cpi * 4) * LL + n0 + lp * 4;
            f32x4 x0 = *(const f32x4*)(xp);
            f32x4 x1 = *(const f32x4*)(xp + LL);
            f32x4 x2 = *(const f32x4*)(xp + 2 * LL);
            f32x4 x3 = *(const f32x4*)(xp + 3 * LL);
#pragma unroll
            for (int u = 0; u < 4; u++) {
                us4 w;
                w[0] = f2bf(x0[u]); w[1] = f2bf(x1[u]);
                w[2] = f2bf(x2[u]); w[3] = f2bf(x3[u]);
                *(us4*)(Bs + (lp * 4 + u) * 72 + cpi * 4) = w;
            }
        }
        __syncthreads();

        short8 aF[4][2], bF[4][2];
#pragma unroll
        for (int mt = 0; mt < 4; mt++) {
            aF[mt][0] = *(const short8*)(As + (wm + mt*16 + ln) * 72 + q * 8);
            aF[mt][1] = *(const short8*)(As + (wm + mt*16 + ln) * 72 + 32 + q * 8);
        }
#pragma unroll
        for (int nt = 0; nt < 4; nt++) {
            bF[nt][0] = *(const short8*)(Bs + (wn + nt*16 + ln) * 72 + q * 8);
            bF[nt][1] = *(const short8*)(Bs + (wn + nt*16 + ln) * 72 + 32 + q * 8);
        }
#pragma unroll
        for (int mt = 0; mt < 4; mt++)
#pragma unroll
            for (int nt = 0; nt < 4; nt++) {
                acc[mt][nt] = __builtin_amdgcn_mfma_f32_16x16x32_bf16(aF[mt][0], bF[nt][0], acc[mt][nt], 0, 0, 0);
                acc[mt][nt] = __builtin_amdgcn_mfma_f32_16x16x32_bf16(aF[mt][1], bF[nt][1], acc[mt][nt], 0, 0, 0);
            }
    }

    const float oscale = (p == 0) ? 0.125f : 1.0f;   // fold 1/sqrt(DH) into Q (exact pow2)
    // epilogue: D layout col = lane&15 (= l), row = q*4+reg (= o)
#pragma unroll
    for (int mt = 0; mt < 4; mt++) {
        const int o_base = m0 + wm + mt * 16 + q * 4;
        float bsf[4];
#pragma unroll
        for (int r = 0; r < 4; r++) bsf[r] = bias[o_base + r];
#pragma unroll
        for (int nt = 0; nt < 4; nt++) {
            const int l = n0 + wn + nt * 16 + ln;
            if (p == 2) {
#pragma unroll
                for (int r = 0; r < 4; r++)
                    Vb[((size_t)b * CC + o_base + r) * SS + l] = f2bf(acc[mt][nt][r] + bsf[r]);
            } else {
                const int h = o_base >> 6;
                const int d = o_base & 63;
                u16* dst = (p == 0) ? Qb : Kb;
                us4 pk;
#pragma unroll
                for (int r = 0; r < 4; r++) pk[r] = (u16)f2bf((acc[mt][nt][r] + bsf[r]) * oscale);
                *(us4*)(dst + ((size_t)(b * HH + h) * TT + l) * 64 + d) = pk;
            }
        }
    }
}

// ---------- flash attention (S^T = K·Q^T; software-pipelined s-loop) ----------
// Q [b][h][t][64] (pre-scaled), K [b][h][s][64], V [b][o][s] (bf16); masks fp32; out fp32 [b][c][t]
__global__ __launch_bounds__(256) void attn_k(
    const u16* __restrict__ Qb, const u16* __restrict__ Kb, const u16* __restrict__ Vb,
    const float* __restrict__ tmask, const float* __restrict__ smask,
    float* __restrict__ out)
{
    __shared__ __align__(16) u16 p_lds[4][16 * 72];   // per-wave P^T rows [t_local][s_local]
    const int tid  = threadIdx.x;
    const int wid  = tid >> 6;
    const int lane = tid & 63;
    const int ln   = lane & 15;
    const int q    = lane >> 4;
    const int b    = blockIdx.z;
    const int h    = blockIdx.y;
    const int t0   = blockIdx.x * 64 + wid * 16;
    const size_t bh = (size_t)b * HH + h;
    const u16* Qp = Qb + bh * TT * 64;
    const u16* Kp = Kb + bh * SS * 64;
    const u16* Vp = Vb + ((size_t)b * CC + h * 64) * SS;
    const float* smb = smask + (size_t)b * SS;

    // Q as B-operand: B[n=t=ln][k=d chunk q*8]
    short8 qB0 = *(const short8*)(Qp + (size_t)(t0 + ln) * 64 + q * 8);
    short8 qB1 = *(const short8*)(Qp + (size_t)(t0 + ln) * 64 + 32 + q * 8);

    const float tm = tmask[(size_t)b * TT + t0 + ln];   // this lane's t-row mask

    float mR = -3.0e38f, lR = 0.f;
    f32x4 oA[4];   // PV accum: D[row=d_local=q*4+r (+dt*16)][col=t=ln]
#pragma unroll
    for (int dt = 0; dt < 4; dt++) oA[dt] = (f32x4){0.f, 0.f, 0.f, 0.f};

    u16* pl = p_lds[wid];
    const f32x4 z = (f32x4){0.f, 0.f, 0.f, 0.f};

    // prefetch tile 0: K frags + smask
    short8 kA0[4], kA1[4];
    f32x4 smv[4];
#pragma unroll
    for (int nt = 0; nt < 4; nt++) {
        kA0[nt] = *(const short8*)(Kp + (size_t)(nt*16 + ln) * 64 + q * 8);
        kA1[nt] = *(const short8*)(Kp + (size_t)(nt*16 + ln) * 64 + 32 + q * 8);
        smv[nt] = *(const f32x4*)(smb + nt * 16 + q * 4);
    }

    for (int s0 = 0; s0 < SS; s0 += 64) {
        // S^T tile: row = s_local = q*4+r (+nt*16), col = t = ln   (consumes kA -> dead after)
        f32x4 sc[4];
#pragma unroll
        for (int nt = 0; nt < 4; nt++) {
            sc[nt] = __builtin_amdgcn_mfma_f32_16x16x32_bf16(kA0[nt], qB0, z, 0, 0, 0);
            sc[nt] = __builtin_amdgcn_mfma_f32_16x16x32_bf16(kA1[nt], qB1, sc[nt], 0, 0, 0);
        }

        // issue next-tile K/smask prefetch (wrapped on last iter; harmless re-read of tile 0)
        const int sn = (s0 + 64) & (SS - 1);
        short8 kN0[4], kN1[4];
        f32x4 smN[4];
#pragma unroll
        for (int nt = 0; nt < 4; nt++) {
            kN0[nt] = *(const short8*)(Kp + (size_t)(sn + nt*16 + ln) * 64 + q * 8);
            kN1[nt] = *(const short8*)(Kp + (size_t)(sn + nt*16 + ln) * 64 + 32 + q * 8);
            smN[nt] = *(const f32x4*)(smb + sn + nt * 16 + q * 4);
        }
        // issue current-tile V loads early: consumed only at PV, covered by softmax latency
        short8 v0[4], v1[4];
#pragma unroll
        for (int dt = 0; dt < 4; dt++) {
            v0[dt] = *(const short8*)(Vp + (size_t)(dt*16 + ln) * SS + s0 + q * 8);
            v1[dt] = *(const short8*)(Vp + (size_t)(dt*16 + ln) * SS + s0 + 32 + q * 8);
        }

        // mask exactly as reference (scale folded into Q): avail*dot - (1-avail)*1e6
        // NOTE: keep this exact form — (dot+1e6)-1e6 quantizes logits to 1/16 (round-6 regression)
#pragma unroll
        for (int nt = 0; nt < 4; nt++)
#pragma unroll
            for (int r = 0; r < 4; r++) {
                float avail = tm * smv[nt][r];
                sc[nt][r] = avail * sc[nt][r] - (1.0f - avail) * 1.0e6f;
            }
        // row-max over 64 s: 16 in-lane + xor across the 4 q-groups
        float m4[4];
#pragma unroll
        for (int nt = 0; nt < 4; nt++)
            m4[nt] = fmaxf(fmaxf(sc[nt][0], sc[nt][1]), fmaxf(sc[nt][2], sc[nt][3]));
        float m_ = fmaxf(fmaxf(m4[0], m4[1]), fmaxf(m4[2], m4[3]));
        m_ = fmaxf(m_, __shfl_xor(m_, 16, 64));
        m_ = fmaxf(m_, __shfl_xor(m_, 32, 64));

        float mN = fmaxf(mR, m_);
        float al = __expf(mR - mN);
        mR = mN;

        float s4[4];
#pragma unroll
        for (int nt = 0; nt < 4; nt++) {
#pragma unroll
            for (int r = 0; r < 4; r++) {
                float pv = __expf(sc[nt][r] - mN);
                sc[nt][r] = pv;
            }
            s4[nt] = (sc[nt][0] + sc[nt][1]) + (sc[nt][2] + sc[nt][3]);
        }
        float s_ = (s4[0] + s4[1]) + (s4[2] + s4[3]);
        s_ += __shfl_xor(s_, 16, 64);
        s_ += __shfl_xor(s_, 32, 64);
        lR = lR * al + s_;
#pragma unroll
        for (int dt = 0; dt < 4; dt++) oA[dt] *= al;

        // P^T -> LDS rows [t=ln][s]: r=0..3 are s-consecutive -> packed 8B writes.
        // DS ops are FIFO per wave; compiler inserts the lgkmcnt before pB use.
#pragma unroll
        for (int nt = 0; nt < 4; nt++) {
            us4 w;
#pragma unroll
            for (int r = 0; r < 4; r++) w[r] = f2bf(sc[nt][r]);
            *(us4*)(pl + ln * 72 + nt * 16 + q * 4) = w;
        }
        // P as B-operand: B[n=t=ln][k=s chunk q*8]
        short8 pB0 = *(const short8*)(pl + ln * 72 + q * 8);
        short8 pB1 = *(const short8*)(pl + ln * 72 + 32 + q * 8);
#pragma unroll
        for (int dt = 0; dt < 4; dt++) {
            // V as A-operand: A[m=d=dt*16+ln][k=s]
            oA[dt] = __builtin_amdgcn_mfma_f32_16x16x32_bf16(v0[dt], pB0, oA[dt], 0, 0, 0);
            oA[dt] = __builtin_amdgcn_mfma_f32_16x16x32_bf16(v1[dt], pB1, oA[dt], 0, 0, 0);
        }

        // rotate prefetched tile into place
#pragma unroll
        for (int nt = 0; nt < 4; nt++) {
            kA0[nt] = kN0[nt]; kA1[nt] = kN1[nt]; smv[nt] = smN[nt];
        }
    }

    const float inv = 1.0f / lR;
    // D: row = d = dt*16 + q*4 + r, col = t = t0 + ln
#pragma unroll
    for (int dt = 0; dt < 4; dt++)
#pragma unroll
        for (int r = 0; r < 4; r++)
            out[((size_t)b * CC + h * 64 + dt * 16 + q * 4 + r) * TT + t0 + ln] =
                oA[dt][r] * inv;
}

extern "C" void kernel_launch(void* const* d_in, const int* in_sizes, int n_in,
                              void* d_out, int out_size, void* d_ws, size_t ws_size,
                              hipStream_t stream)
{
    const float* target = (const float*)d_in[0];
    const float* source = (const float*)d_in[1];
    const float* tmask  = (const float*)d_in[2];
    const float* smask  = (const float*)d_in[3];
    const float* Wq = (const float*)d_in[4];
    const float* bq = (const float*)d_in[5];
    const float* Wk = (const float*)d_in[6];
    const float* bk = (const float*)d_in[7];
    const float* Wv = (const float*)d_in[8];
    const float* bv = (const float*)d_in[9];

    u16* ws = (u16*)d_ws;
    const size_t N1 = (size_t)BB * CC * TT;   // 4,194,304 elements (8 MB bf16)
    u16* Qb = ws;
    u16* Kb = ws + N1;
    u16* Vb = ws + 2 * N1;                    // total 24 MB

    qkv_gemm<<<dim3(TT/128, CC/128, 6), dim3(256, 1, 1), 0, stream>>>(
        target, source, Wq, bq, Wk, bk, Wv, bv, Qb, Kb, Vb);
    attn_k<<<dim3(TT/64, HH, BB), dim3(256, 1, 1), 0, stream>>>(
        Qb, Kb, Vb, tmask, smask, (float*)d_out);
}

// Round 9
// 254.915 us; speedup vs baseline: 1.6169x; 1.6169x over previous
//
#include <hip/hip_runtime.h>

#define BB 2
#define CC 1024
#define HH 16
#define TT 2048
#define SS 2048
#define LL 2048   // T == S

typedef unsigned short u16;
typedef __attribute__((ext_vector_type(8))) short short8;
typedef __attribute__((ext_vector_type(4))) float f32x4;
typedef __attribute__((ext_vector_type(4))) unsigned short us4;

__device__ __forceinline__ u16 f2bf(float f) {
    union { float f; unsigned int i; } x; x.f = f;
    unsigned int r = x.i + 0x7FFFu + ((x.i >> 16) & 1u);
    return (u16)(r >> 16);
}

// ---------- QKV projection GEMM (transpose fused into B staging) ----------
// Out[o][l] = sum_c W[o][c] * X[b][c][l] + bias[o]   (fp32 in, bf16 out)
// p=0: Q*0.125 -> Qb [b][h][t][64]; p=1: K -> Kb [b][h][s][64]; p=2: V -> Vb [b][o][s]
__global__ __launch_bounds__(256) void qkv_gemm(
    const float* __restrict__ target, const float* __restrict__ source,
    const float* __restrict__ Wq, const float* __restrict__ bq,
    const float* __restrict__ Wk, const float* __restrict__ bk,
    const float* __restrict__ Wv, const float* __restrict__ bv,
    u16* __restrict__ Qb, u16* __restrict__ Kb, u16* __restrict__ Vb)
{
    const int p = blockIdx.z >> 1;
    const int b = blockIdx.z & 1;
    const float* W    = (p == 0) ? Wq : (p == 1) ? Wk : Wv;
    const float* bias = (p == 0) ? bq : (p == 1) ? bk : bv;
    const float* X    = ((p == 0) ? target : source) + (size_t)b * CC * LL;

    const int m0 = blockIdx.y * 128;   // o
    const int n0 = blockIdx.x * 128;   // l (token)

    __shared__ __align__(16) u16 As[128 * 72];  // As[o_local][c_local]
    __shared__ __align__(16) u16 Bs[128 * 72];  // Bs[l_local][c_local]

    const int tid  = threadIdx.x;
    const int lane = tid & 63;
    const int wid  = tid >> 6;
    const int ln   = lane & 15;
    const int q    = lane >> 4;
    const int wm   = (wid >> 1) * 64;
    const int wn   = (wid & 1) * 64;

    f32x4 acc[4][4];
#pragma unroll
    for (int i = 0; i < 4; i++)
#pragma unroll
        for (int j = 0; j < 4; j++) acc[i][j] = (f32x4){0.f, 0.f, 0.f, 0.f};

    const int arow_s = tid >> 3;       // 0..31
    const int ach    = tid & 7;        // 8-elem chunk within 64-elem c-slab
    const int lp     = tid & 31;       // l-patch (4 l each)
    const int cp0    = tid >> 5;       // 0..7 (c-patch base)

    for (int k0 = 0; k0 < CC; k0 += 64) {
        __syncthreads();
        // --- stage A: W[o][c] fp32 -> bf16, row-major ---
#pragma unroll
        for (int i = 0; i < 4; i++) {
            const int row = arow_s + i * 32;
            const float* wp = W + (size_t)(m0 + row) * CC + k0 + ach * 8;
            f32x4 w0 = *(const f32x4*)wp;
            f32x4 w1 = *(const f32x4*)(wp + 4);
            short8 av;
#pragma unroll
            for (int j = 0; j < 4; j++) { av[j] = (short)f2bf(w0[j]); av[4 + j] = (short)f2bf(w1[j]); }
            *(short8*)(As + row * 72 + ach * 8) = av;
        }
        // --- stage B with transpose: X[c][l] fp32 -> Bs[l][c] bf16, 4x4 patches ---
#pragma unroll
        for (int i = 0; i < 2; i++) {
            const int cpi = cp0 + i * 8;    // c-patch 0..15 (4 c each)
            const float* xp = X + (size_t)(k0 + cpi * 4) * LL + n0 + lp * 4;
            f32x4 x0 = *(const f32x4*)(xp);
            f32x4 x1 = *(const f32x4*)(xp + LL);
            f32x4 x2 = *(const f32x4*)(xp + 2 * LL);
            f32x4 x3 = *(const f32x4*)(xp + 3 * LL);
#pragma unroll
            for (int u = 0; u < 4; u++) {
                us4 w;
                w[0] = f2bf(x0[u]); w[1] = f2bf(x1[u]);
                w[2] = f2bf(x2[u]); w[3] = f2bf(x3[u]);
                *(us4*)(Bs + (lp * 4 + u) * 72 + cpi * 4) = w;
            }
        }
        __syncthreads();

        short8 aF[4][2], bF[4][2];
#pragma unroll
        for (int mt = 0; mt < 4; mt++) {
            aF[mt][0] = *(const short8*)(As + (wm + mt*16 + ln) * 72 + q * 8);
            aF[mt][1] = *(const short8*)(As + (wm + mt*16 + ln) * 72 + 32 + q * 8);
        }
#pragma unroll
        for (int nt = 0; nt < 4; nt++) {
            bF[nt][0] = *(const short8*)(Bs + (wn + nt*16 + ln) * 72 + q * 8);
            bF[nt][1] = *(const short8*)(Bs + (wn + nt*16 + ln) * 72 + 32 + q * 8);
        }
#pragma unroll
        for (int mt = 0; mt < 4; mt++)
#pragma unroll
            for (int nt = 0; nt < 4; nt++) {
                acc[mt][nt] = __builtin_amdgcn_mfma_f32_16x16x32_bf16(aF[mt][0], bF[nt][0], acc[mt][nt], 0, 0, 0);
                acc[mt][nt] = __builtin_amdgcn_mfma_f32_16x16x32_bf16(aF[mt][1], bF[nt][1], acc[mt][nt], 0, 0, 0);
            }
    }

    const float oscale = (p == 0) ? 0.125f : 1.0f;   // fold 1/sqrt(DH) into Q (exact pow2)
    // epilogue: D layout col = lane&15 (= l), row = q*4+reg (= o)
#pragma unroll
    for (int mt = 0; mt < 4; mt++) {
        const int o_base = m0 + wm + mt * 16 + q * 4;
        float bsf[4];
#pragma unroll
        for (int r = 0; r < 4; r++) bsf[r] = bias[o_base + r];
#pragma unroll
        for (int nt = 0; nt < 4; nt++) {
            const int l = n0 + wn + nt * 16 + ln;
            if (p == 2) {
#pragma unroll
                for (int r = 0; r < 4; r++)
                    Vb[((size_t)b * CC + o_base + r) * SS + l] = f2bf(acc[mt][nt][r] + bsf[r]);
            } else {
                const int h = o_base >> 6;
                const int d = o_base & 63;
                u16* dst = (p == 0) ? Qb : Kb;
                us4 pk;
#pragma unroll
                for (int r = 0; r < 4; r++) pk[r] = (u16)f2bf((acc[mt][nt][r] + bsf[r]) * oscale);
                *(us4*)(dst + ((size_t)(b * HH + h) * TT + l) * 64 + d) = pk;
            }
        }
    }
}

// ---------- flash attention (S^T = K·Q^T; block-cooperative LDS K/V staging) ----------
// Q [b][h][t][64] (pre-scaled), K [b][h][s][64], V [b][o][s] (bf16); masks fp32; out fp32 [b][c][t]
__global__ __launch_bounds__(256) void attn_k(
    const u16* __restrict__ Qb, const u16* __restrict__ Kb, const u16* __restrict__ Vb,
    const float* __restrict__ tmask, const float* __restrict__ smask,
    float* __restrict__ out)
{
    __shared__ __align__(16) u16 Ks[64 * 72];         // K tile rows s_local, cols d
    __shared__ __align__(16) u16 Vs[64 * 72];         // V tile rows d,       cols s_local
    __shared__ __align__(16) u16 p_lds[4][16 * 72];   // per-wave P^T rows [t_local][s_local]
    const int tid  = threadIdx.x;
    const int wid  = tid >> 6;
    const int lane = tid & 63;
    const int ln   = lane & 15;
    const int q    = lane >> 4;
    const int b    = blockIdx.z;
    const int h    = blockIdx.y;
    const int t0   = blockIdx.x * 64 + wid * 16;
    const size_t bh = (size_t)b * HH + h;
    const u16* Qp = Qb + bh * TT * 64;
    const u16* Kp = Kb + bh * SS * 64;
    const u16* Vp = Vb + ((size_t)b * CC + h * 64) * SS;
    const float* smb = smask + (size_t)b * SS;

    // staging role: 4 threads per row, 16 u16 (32 B) each
    const int srow = tid >> 2;          // 0..63
    const int sseg = (tid & 3) * 16;    // u16 offset {0,16,32,48}

    // Q as B-operand: B[n=t=ln][k=d chunk q*8]
    short8 qB0 = *(const short8*)(Qp + (size_t)(t0 + ln) * 64 + q * 8);
    short8 qB1 = *(const short8*)(Qp + (size_t)(t0 + ln) * 64 + 32 + q * 8);

    const float tm = tmask[(size_t)b * TT + t0 + ln];   // this lane's t-row mask

    float mR = -3.0e38f, lR = 0.f;
    f32x4 oA[4];   // PV accum: D[row=d_local=q*4+r (+dt*16)][col=t=ln]
#pragma unroll
    for (int dt = 0; dt < 4; dt++) oA[dt] = (f32x4){0.f, 0.f, 0.f, 0.f};

    u16* pl = p_lds[wid];
    const f32x4 z = (f32x4){0.f, 0.f, 0.f, 0.f};

    for (int s0 = 0; s0 < SS; s0 += 64) {
        __syncthreads();   // previous tile's frag reads complete before overwrite
        // --- cooperative staging: K rows contiguous (coalesced), V rows SS-strided ---
        {
            const u16* kg = Kp + (size_t)(s0 + srow) * 64 + sseg;
            short8 k0 = *(const short8*)kg;
            short8 k1 = *(const short8*)(kg + 8);
            const u16* vg = Vp + (size_t)srow * SS + s0 + sseg;
            short8 vv0 = *(const short8*)vg;
            short8 vv1 = *(const short8*)(vg + 8);
            *(short8*)(Ks + srow * 72 + sseg)     = k0;
            *(short8*)(Ks + srow * 72 + sseg + 8) = k1;
            *(short8*)(Vs + srow * 72 + sseg)     = vv0;
            *(short8*)(Vs + srow * 72 + sseg + 8) = vv1;
        }
        __syncthreads();

        // S^T tile: row = s_local = q*4+r (+nt*16), col = t = ln
        f32x4 sc[4];
        f32x4 smv[4];
#pragma unroll
        for (int nt = 0; nt < 4; nt++) {
            short8 k0 = *(const short8*)(Ks + (nt*16 + ln) * 72 + q * 8);
            short8 k1 = *(const short8*)(Ks + (nt*16 + ln) * 72 + 32 + q * 8);
            sc[nt] = __builtin_amdgcn_mfma_f32_16x16x32_bf16(k0, qB0, z, 0, 0, 0);
            sc[nt] = __builtin_amdgcn_mfma_f32_16x16x32_bf16(k1, qB1, sc[nt], 0, 0, 0);
            smv[nt] = *(const f32x4*)(smb + s0 + nt * 16 + q * 4);
        }

        // mask exactly as reference (scale folded into Q): avail*dot - (1-avail)*1e6
        // NOTE: keep this exact form — (dot+1e6)-1e6 quantizes logits to 1/16 (round-6 regression)
#pragma unroll
        for (int nt = 0; nt < 4; nt++)
#pragma unroll
            for (int r = 0; r < 4; r++) {
                float avail = tm * smv[nt][r];
                sc[nt][r] = avail * sc[nt][r] - (1.0f - avail) * 1.0e6f;
            }
        // row-max over 64 s: 16 in-lane + xor across the 4 q-groups
        float m4[4];
#pragma unroll
        for (int nt = 0; nt < 4; nt++)
            m4[nt] = fmaxf(fmaxf(sc[nt][0], sc[nt][1]), fmaxf(sc[nt][2], sc[nt][3]));
        float m_ = fmaxf(fmaxf(m4[0], m4[1]), fmaxf(m4[2], m4[3]));
        m_ = fmaxf(m_, __shfl_xor(m_, 16, 64));
        m_ = fmaxf(m_, __shfl_xor(m_, 32, 64));

        float mN = fmaxf(mR, m_);
        float al = __expf(mR - mN);
        mR = mN;

        float s4[4];
#pragma unroll
        for (int nt = 0; nt < 4; nt++) {
#pragma unroll
            for (int r = 0; r < 4; r++) {
                float pv = __expf(sc[nt][r] - mN);
                sc[nt][r] = pv;
            }
            s4[nt] = (sc[nt][0] + sc[nt][1]) + (sc[nt][2] + sc[nt][3]);
        }
        float s_ = (s4[0] + s4[1]) + (s4[2] + s4[3]);
        s_ += __shfl_xor(s_, 16, 64);
        s_ += __shfl_xor(s_, 32, 64);
        lR = lR * al + s_;
#pragma unroll
        for (int dt = 0; dt < 4; dt++) oA[dt] *= al;

        // P^T -> per-wave LDS rows [t=ln][s]: r=0..3 are s-consecutive -> packed 8B writes.
        // DS ops are FIFO per wave; compiler inserts the lgkmcnt before pB use (R8 verified).
#pragma unroll
        for (int nt = 0; nt < 4; nt++) {
            us4 w;
#pragma unroll
            for (int r = 0; r < 4; r++) w[r] = f2bf(sc[nt][r]);
            *(us4*)(pl + ln * 72 + nt * 16 + q * 4) = w;
        }
        // P as B-operand: B[n=t=ln][k=s chunk q*8]
        short8 pB0 = *(const short8*)(pl + ln * 72 + q * 8);
        short8 pB1 = *(const short8*)(pl + ln * 72 + 32 + q * 8);
#pragma unroll
        for (int dt = 0; dt < 4; dt++) {
            // V as A-operand: A[m=d=dt*16+ln][k=s chunk q*8]
            short8 v0 = *(const short8*)(Vs + (dt*16 + ln) * 72 + q * 8);
            short8 v1 = *(const short8*)(Vs + (dt*16 + ln) * 72 + 32 + q * 8);
            oA[dt] = __builtin_amdgcn_mfma_f32_16x16x32_bf16(v0, pB0, oA[dt], 0, 0, 0);
            oA[dt] = __builtin_amdgcn_mfma_f32_16x16x32_bf16(v1, pB1, oA[dt], 0, 0, 0);
        }
    }

    const float inv = 1.0f / lR;
    // D: row = d = dt*16 + q*4 + r, col = t = t0 + ln
#pragma unroll
    for (int dt = 0; dt < 4; dt++)
#pragma unroll
        for (int r = 0; r < 4; r++)
            out[((size_t)b * CC + h * 64 + dt * 16 + q * 4 + r) * TT + t0 + ln] =
                oA[dt][r] * inv;
}

extern "C" void kernel_launch(void* const* d_in, const int* in_sizes, int n_in,
                              void* d_out, int out_size, void* d_ws, size_t ws_size,
                              hipStream_t stream)
{
    const float* target = (const float*)d_in[0];
    const float* source = (const float*)d_in[1];
    const float* tmask  = (const float*)d_in[2];
    const float* smask  = (const float*)d_in[3];
    const float* Wq = (const float*)d_in[4];
    const float* bq = (const float*)d_in[5];
    const float* Wk = (const float*)d_in[6];
    const float* bk = (const float*)d_in[7];
    const float* Wv = (const float*)d_in[8];
    const float* bv = (const float*)d_in[9];

    u16* ws = (u16*)d_ws;
    const size_t N1 = (size_t)BB * CC * TT;   // 4,194,304 elements (8 MB bf16)
    u16* Qb = ws;
    u16* Kb = ws + N1;
    u16* Vb = ws + 2 * N1;                    // total 24 MB

    qkv_gemm<<<dim3(TT/128, CC/128, 6), dim3(256, 1, 1), 0, stream>>>(
        target, source, Wq, bq, Wk, bk, Wv, bv, Qb, Kb, Vb);
    attn_k<<<dim3(TT/64, HH, BB), dim3(256, 1, 1), 0, stream>>>(
        Qb, Kb, Vb, tmask, smask, (float*)d_out);
}

// Round 10
// 251.147 us; speedup vs baseline: 1.6411x; 1.0150x over previous
//
#include <hip/hip_runtime.h>

#define BB 2
#define CC 1024
#define HH 16
#define TT 2048
#define SS 2048
#define LL 2048   // T == S

typedef unsigned short u16;
typedef unsigned int u32;
typedef __attribute__((ext_vector_type(8))) short short8;
typedef __attribute__((ext_vector_type(4))) float f32x4;
typedef __attribute__((ext_vector_type(4))) unsigned short us4;
typedef __attribute__((ext_vector_type(2))) unsigned int u32x2;

__device__ __forceinline__ u16 f2bf(float f) {
    union { float f; unsigned int i; } x; x.f = f;
    unsigned int r = x.i + 0x7FFFu + ((x.i >> 16) & 1u);
    return (u16)(r >> 16);
}
// pack two floats -> two bf16 (round-half-up; P in [0,1], bias negligible)
__device__ __forceinline__ u32 pk2bf(float a, float b) {
    u32 ia = __float_as_uint(a) + 0x8000u;
    u32 ib = __float_as_uint(b) + 0x8000u;
    return (ia >> 16) | (ib & 0xFFFF0000u);
}
__device__ __forceinline__ float exp2_hw(float x) {
    float r;
    asm("v_exp_f32 %0, %1" : "=v"(r) : "v"(x));
    return r;
}

// ---------- QKV projection GEMM (transpose fused into B staging) ----------
// Out[o][l] = sum_c W[o][c] * X[b][c][l] + bias[o]   (fp32 in, bf16 out)
// p=0: Q*(0.125*log2e) -> Qb [b][h][t][64]; p=1: K -> Kb; p=2: V -> Vb [b][o][s]
__global__ __launch_bounds__(256) void qkv_gemm(
    const float* __restrict__ target, const float* __restrict__ source,
    const float* __restrict__ Wq, const float* __restrict__ bq,
    const float* __restrict__ Wk, const float* __restrict__ bk,
    const float* __restrict__ Wv, const float* __restrict__ bv,
    u16* __restrict__ Qb, u16* __restrict__ Kb, u16* __restrict__ Vb)
{
    const int p = blockIdx.z >> 1;
    const int b = blockIdx.z & 1;
    const float* W    = (p == 0) ? Wq : (p == 1) ? Wk : Wv;
    const float* bias = (p == 0) ? bq : (p == 1) ? bk : bv;
    const float* X    = ((p == 0) ? target : source) + (size_t)b * CC * LL;

    const int m0 = blockIdx.y * 128;   // o
    const int n0 = blockIdx.x * 128;   // l (token)

    __shared__ __align__(16) u16 As[128 * 72];  // As[o_local][c_local]
    __shared__ __align__(16) u16 Bs[128 * 72];  // Bs[l_local][c_local]

    const int tid  = threadIdx.x;
    const int lane = tid & 63;
    const int wid  = tid >> 6;
    const int ln   = lane & 15;
    const int q    = lane >> 4;
    const int wm   = (wid >> 1) * 64;
    const int wn   = (wid & 1) * 64;

    f32x4 acc[4][4];
#pragma unroll
    for (int i = 0; i < 4; i++)
#pragma unroll
        for (int j = 0; j < 4; j++) acc[i][j] = (f32x4){0.f, 0.f, 0.f, 0.f};

    const int arow_s = tid >> 3;       // 0..31
    const int ach    = tid & 7;        // 8-elem chunk within 64-elem c-slab
    const int lp     = tid & 31;       // l-patch (4 l each)
    const int cp0    = tid >> 5;       // 0..7 (c-patch base)

    for (int k0 = 0; k0 < CC; k0 += 64) {
        __syncthreads();
        // --- stage A: W[o][c] fp32 -> bf16, row-major ---
#pragma unroll
        for (int i = 0; i < 4; i++) {
            const int row = arow_s + i * 32;
            const float* wp = W + (size_t)(m0 + row) * CC + k0 + ach * 8;
            f32x4 w0 = *(const f32x4*)wp;
            f32x4 w1 = *(const f32x4*)(wp + 4);
            short8 av;
#pragma unroll
            for (int j = 0; j < 4; j++) { av[j] = (short)f2bf(w0[j]); av[4 + j] = (short)f2bf(w1[j]); }
            *(short8*)(As + row * 72 + ach * 8) = av;
        }
        // --- stage B with transpose: X[c][l] fp32 -> Bs[l][c] bf16, 4x4 patches ---
#pragma unroll
        for (int i = 0; i < 2; i++) {
            const int cpi = cp0 + i * 8;    // c-patch 0..15 (4 c each)
            const float* xp = X + (size_t)(k0 + cpi * 4) * LL + n0 + lp * 4;
            f32x4 x0 = *(const f32x4*)(xp);
            f32x4 x1 = *(const f32x4*)(xp + LL);
            f32x4 x2 = *(const f32x4*)(xp + 2 * LL);
            f32x4 x3 = *(const f32x4*)(xp + 3 * LL);
#pragma unroll
            for (int u = 0; u < 4; u++) {
                us4 w;
                w[0] = f2bf(x0[u]); w[1] = f2bf(x1[u]);
                w[2] = f2bf(x2[u]); w[3] = f2bf(x3[u]);
                *(us4*)(Bs + (lp * 4 + u) * 72 + cpi * 4) = w;
            }
        }
        __syncthreads();

        short8 aF[4][2], bF[4][2];
#pragma unroll
        for (int mt = 0; mt < 4; mt++) {
            aF[mt][0] = *(const short8*)(As + (wm + mt*16 + ln) * 72 + q * 8);
            aF[mt][1] = *(const short8*)(As + (wm + mt*16 + ln) * 72 + 32 + q * 8);
        }
#pragma unroll
        for (int nt = 0; nt < 4; nt++) {
            bF[nt][0] = *(const short8*)(Bs + (wn + nt*16 + ln) * 72 + q * 8);
            bF[nt][1] = *(const short8*)(Bs + (wn + nt*16 + ln) * 72 + 32 + q * 8);
        }
#pragma unroll
        for (int mt = 0; mt < 4; mt++)
#pragma unroll
            for (int nt = 0; nt < 4; nt++) {
                acc[mt][nt] = __builtin_amdgcn_mfma_f32_16x16x32_bf16(aF[mt][0], bF[nt][0], acc[mt][nt], 0, 0, 0);
                acc[mt][nt] = __builtin_amdgcn_mfma_f32_16x16x32_bf16(aF[mt][1], bF[nt][1], acc[mt][nt], 0, 0, 0);
            }
    }

    // Q folds 1/sqrt(DH) * log2(e): softmax runs in log2 domain (exp2 HW op)
    const float oscale = (p == 0) ? 0.18033688011112042f : 1.0f;
    // epilogue: D layout col = lane&15 (= l), row = q*4+reg (= o)
#pragma unroll
    for (int mt = 0; mt < 4; mt++) {
        const int o_base = m0 + wm + mt * 16 + q * 4;
        float bsf[4];
#pragma unroll
        for (int r = 0; r < 4; r++) bsf[r] = bias[o_base + r];
#pragma unroll
        for (int nt = 0; nt < 4; nt++) {
            const int l = n0 + wn + nt * 16 + ln;
            if (p == 2) {
#pragma unroll
                for (int r = 0; r < 4; r++)
                    Vb[((size_t)b * CC + o_base + r) * SS + l] = f2bf(acc[mt][nt][r] + bsf[r]);
            } else {
                const int h = o_base >> 6;
                const int d = o_base & 63;
                u16* dst = (p == 0) ? Qb : Kb;
                us4 pk;
#pragma unroll
                for (int r = 0; r < 4; r++) pk[r] = (u16)f2bf((acc[mt][nt][r] + bsf[r]) * oscale);
                *(us4*)(dst + ((size_t)(b * HH + h) * TT + l) * 64 + d) = pk;
            }
        }
    }
}

// ---------- flash attention (S^T = K·Q^T; LDS K/V staging; log2-domain softmax) ----------
// Q [b][h][t][64] (pre-scaled by 0.125*log2e), K [b][h][s][64], V [b][o][s] (bf16);
// masks fp32 (binary); out fp32 [b][c][t]
#define C2MASK 1442695.0f   // 1e6 * log2(e)
__global__ __launch_bounds__(256) void attn_k(
    const u16* __restrict__ Qb, const u16* __restrict__ Kb, const u16* __restrict__ Vb,
    const float* __restrict__ tmask, const float* __restrict__ smask,
    float* __restrict__ out)
{
    __shared__ __align__(16) u16 Ks[64 * 72];         // K tile rows s_local, cols d
    __shared__ __align__(16) u16 Vs[64 * 72];         // V tile rows d,       cols s_local
    __shared__ __align__(16) u16 p_lds[4][16 * 72];   // per-wave P^T rows [t_local][s_local]
    const int tid  = threadIdx.x;
    const int wid  = tid >> 6;
    const int lane = tid & 63;
    const int ln   = lane & 15;
    const int q    = lane >> 4;
    // XCD-locality swizzle: all 32 t-tiles of one (b,h) share idx%8 -> same XCD L2
    const int idx   = blockIdx.x;
    const int xcd   = idx & 7;
    const int rest  = idx >> 3;
    const int ttile = rest & 31;
    const int bh    = (rest >> 5) * 8 + xcd;   // 0..31
    const int b     = bh >> 4;
    const int h     = bh & 15;
    const int t0    = ttile * 64 + wid * 16;
    const u16* Qp = Qb + (size_t)bh * TT * 64;
    const u16* Kp = Kb + (size_t)bh * SS * 64;
    const u16* Vp = Vb + ((size_t)b * CC + h * 64) * SS;
    const float* smb = smask + (size_t)b * SS;

    // staging role: 4 threads per row, 16 u16 (32 B) each
    const int srow = tid >> 2;          // 0..63
    const int sseg = (tid & 3) * 16;    // u16 offset {0,16,32,48}

    // Q as B-operand: B[n=t=ln][k=d chunk q*8]
    short8 qB0 = *(const short8*)(Qp + (size_t)(t0 + ln) * 64 + q * 8);
    short8 qB1 = *(const short8*)(Qp + (size_t)(t0 + ln) * 64 + 32 + q * 8);

    const float tm = tmask[(size_t)b * TT + t0 + ln];   // this lane's t-row mask (binary)

    float mR = -3.0e38f, lR = 0.f;
    f32x4 oA[4];   // PV accum: D[row=d_local=q*4+r (+dt*16)][col=t=ln]
#pragma unroll
    for (int dt = 0; dt < 4; dt++) oA[dt] = (f32x4){0.f, 0.f, 0.f, 0.f};

    u16* pl = p_lds[wid];
    const f32x4 z = (f32x4){0.f, 0.f, 0.f, 0.f};

    for (int s0 = 0; s0 < SS; s0 += 64) {
        __syncthreads();   // previous tile's frag reads complete before overwrite
        // --- cooperative staging: K rows contiguous (coalesced), V rows SS-strided ---
        {
            const u16* kg = Kp + (size_t)(s0 + srow) * 64 + sseg;
            short8 k0 = *(const short8*)kg;
            short8 k1 = *(const short8*)(kg + 8);
            const u16* vg = Vp + (size_t)srow * SS + s0 + sseg;
            short8 vv0 = *(const short8*)vg;
            short8 vv1 = *(const short8*)(vg + 8);
            *(short8*)(Ks + srow * 72 + sseg)     = k0;
            *(short8*)(Ks + srow * 72 + sseg + 8) = k1;
            *(short8*)(Vs + srow * 72 + sseg)     = vv0;
            *(short8*)(Vs + srow * 72 + sseg + 8) = vv1;
        }
        __syncthreads();

        // S^T tile (log2 domain): row = s_local = q*4+r (+nt*16), col = t = ln
        f32x4 sc[4];
        f32x4 smv[4];
#pragma unroll
        for (int nt = 0; nt < 4; nt++) {
            short8 k0 = *(const short8*)(Ks + (nt*16 + ln) * 72 + q * 8);
            short8 k1 = *(const short8*)(Ks + (nt*16 + ln) * 72 + 32 + q * 8);
            sc[nt] = __builtin_amdgcn_mfma_f32_16x16x32_bf16(k0, qB0, z, 0, 0, 0);
            sc[nt] = __builtin_amdgcn_mfma_f32_16x16x32_bf16(k1, qB1, sc[nt], 0, 0, 0);
            smv[nt] = *(const f32x4*)(smb + s0 + nt * 16 + q * 4);
        }

        // masks are binary -> exact select (equivalent to avail*dot-(1-avail)*1e6, log2 scaled)
#pragma unroll
        for (int nt = 0; nt < 4; nt++)
#pragma unroll
            for (int r = 0; r < 4; r++) {
                float a = tm * smv[nt][r];
                sc[nt][r] = (a > 0.5f) ? sc[nt][r] : -C2MASK;
            }
        // row-max over 64 s: 15 in-lane + xor across the 4 q-groups
        float m4[4];
#pragma unroll
        for (int nt = 0; nt < 4; nt++)
            m4[nt] = fmaxf(fmaxf(sc[nt][0], sc[nt][1]), fmaxf(sc[nt][2], sc[nt][3]));
        float m_ = fmaxf(fmaxf(m4[0], m4[1]), fmaxf(m4[2], m4[3]));
        m_ = fmaxf(m_, __shfl_xor(m_, 16, 64));
        m_ = fmaxf(m_, __shfl_xor(m_, 32, 64));

        const float mN = fmaxf(mR, m_);
        const bool unchanged = (mN == mR);

        float s4[4];
#pragma unroll
        for (int nt = 0; nt < 4; nt++) {
#pragma unroll
            for (int r = 0; r < 4; r++)
                sc[nt][r] = exp2_hw(sc[nt][r] - mN);
            s4[nt] = (sc[nt][0] + sc[nt][1]) + (sc[nt][2] + sc[nt][3]);
        }
        float s_ = (s4[0] + s4[1]) + (s4[2] + s4[3]);
        s_ += __shfl_xor(s_, 16, 64);
        s_ += __shfl_xor(s_, 32, 64);

        if (__all(unchanged)) {          // running max stable for every row in wave
            lR += s_;
        } else {
            float al = exp2_hw(mR - mN); // ==1.0 exactly for lanes with unchanged max
            lR = lR * al + s_;
#pragma unroll
            for (int dt = 0; dt < 4; dt++) oA[dt] *= al;
        }
        mR = mN;

        // P^T -> per-wave LDS rows [t=ln][s]: packed 8B writes (pair-packed bf16)
#pragma unroll
        for (int nt = 0; nt < 4; nt++) {
            u32x2 w;
            w[0] = pk2bf(sc[nt][0], sc[nt][1]);
            w[1] = pk2bf(sc[nt][2], sc[nt][3]);
            *(u32x2*)(pl + ln * 72 + nt * 16 + q * 4) = w;
        }
        // P as B-operand: B[n=t=ln][k=s chunk q*8]
        short8 pB0 = *(const short8*)(pl + ln * 72 + q * 8);
        short8 pB1 = *(const short8*)(pl + ln * 72 + 32 + q * 8);
#pragma unroll
        for (int dt = 0; dt < 4; dt++) {
            // V as A-operand: A[m=d=dt*16+ln][k=s chunk q*8]
            short8 v0 = *(const short8*)(Vs + (dt*16 + ln) * 72 + q * 8);
            short8 v1 = *(const short8*)(Vs + (dt*16 + ln) * 72 + 32 + q * 8);
            oA[dt] = __builtin_amdgcn_mfma_f32_16x16x32_bf16(v0, pB0, oA[dt], 0, 0, 0);
            oA[dt] = __builtin_amdgcn_mfma_f32_16x16x32_bf16(v1, pB1, oA[dt], 0, 0, 0);
        }
    }

    const float inv = 1.0f / lR;
    // D: row = d = dt*16 + q*4 + r, col = t = t0 + ln
#pragma unroll
    for (int dt = 0; dt < 4; dt++)
#pragma unroll
        for (int r = 0; r < 4; r++)
            out[((size_t)b * CC + h * 64 + dt * 16 + q * 4 + r) * TT + t0 + ln] =
                oA[dt][r] * inv;
}

extern "C" void kernel_launch(void* const* d_in, const int* in_sizes, int n_in,
                              void* d_out, int out_size, void* d_ws, size_t ws_size,
                              hipStream_t stream)
{
    const float* target = (const float*)d_in[0];
    const float* source = (const float*)d_in[1];
    const float* tmask  = (const float*)d_in[2];
    const float* smask  = (const float*)d_in[3];
    const float* Wq = (const float*)d_in[4];
    const float* bq = (const float*)d_in[5];
    const float* Wk = (const float*)d_in[6];
    const float* bk = (const float*)d_in[7];
    const float* Wv = (const float*)d_in[8];
    const float* bv = (const float*)d_in[9];

    u16* ws = (u16*)d_ws;
    const size_t N1 = (size_t)BB * CC * TT;   // 4,194,304 elements (8 MB bf16)
    u16* Qb = ws;
    u16* Kb = ws + N1;
    u16* Vb = ws + 2 * N1;                    // total 24 MB

    qkv_gemm<<<dim3(TT/128, CC/128, 6), dim3(256, 1, 1), 0, stream>>>(
        target, source, Wq, bq, Wk, bk, Wv, bv, Qb, Kb, Vb);
    attn_k<<<dim3(BB*HH*(TT/64), 1, 1), dim3(256, 1, 1), 0, stream>>>(
        Qb, Kb, Vb, tmask, smask, (float*)d_out);
}